// Round 4
// baseline (2210.590 us; speedup 1.0000x reference)
//
#include <hip/hip_runtime.h>
#include <cstdint>
#include <cstddef>

#define XLD 161   // x row stride = NFEAT + EXTRA + 1

typedef float f4u __attribute__((ext_vector_type(4), aligned(4)));   // unaligned-tolerant float4
typedef float f3u __attribute__((ext_vector_type(3), aligned(4)));   // 12-byte vector (dwordx3)
typedef float f2u __attribute__((ext_vector_type(2), aligned(8)));

// ============================ CSR build ============================
__global__ void hist_kernel(const int* __restrict__ row, int* __restrict__ cnt, int E) {
    for (int e = blockIdx.x * blockDim.x + threadIdx.x; e < E; e += gridDim.x * blockDim.x)
        atomicAdd(&cnt[row[e]], 1);
}

__global__ __launch_bounds__(256)
void scan1_kernel(const int* __restrict__ cnt, int* __restrict__ offs,
                  int* __restrict__ bsums, int n) {
    int t = threadIdx.x;
    int gid = blockIdx.x * 256 + t;
    int v = (gid < n) ? cnt[gid] : 0;
    int x = v;
#pragma unroll
    for (int o = 1; o < 64; o <<= 1) { int y = __shfl_up(x, o); if ((t & 63) >= o) x += y; }
    __shared__ int ws[4];
    if ((t & 63) == 63) ws[t >> 6] = x;
    __syncthreads();
    int add = 0;
    for (int w = 0; w < (t >> 6); w++) add += ws[w];
    int incl = x + add;
    if (gid < n) offs[gid] = incl - v;
    if (t == 255) bsums[blockIdx.x] = incl;
}

__global__ __launch_bounds__(256)
void scan2_kernel(int* __restrict__ bsums, int nb) {
    int t = threadIdx.x;
    int v = (t < nb) ? bsums[t] : 0;
    int x = v;
#pragma unroll
    for (int o = 1; o < 64; o <<= 1) { int y = __shfl_up(x, o); if ((t & 63) >= o) x += y; }
    __shared__ int ws[4];
    if ((t & 63) == 63) ws[t >> 6] = x;
    __syncthreads();
    int add = 0;
    for (int w = 0; w < (t >> 6); w++) add += ws[w];
    if (t < nb) bsums[t] = x + add - v;
}

__global__ void scan3_kernel(int* __restrict__ offs, int* __restrict__ cursor,
                             const int* __restrict__ bsums, int n, int E) {
    int gid = blockIdx.x * 256 + threadIdx.x;
    if (gid < n) {
        int o = offs[gid] + bsums[blockIdx.x];
        offs[gid] = o;
        cursor[gid] = o;
    }
    if (gid == 0) offs[n] = E;
}

__global__ void scatter_kernel(const int* __restrict__ row, const int* __restrict__ col,
                               const float* __restrict__ val, int* __restrict__ cursor,
                               int* __restrict__ colA, float* __restrict__ valA, int E) {
    for (int e = blockIdx.x * blockDim.x + threadIdx.x; e < E; e += gridDim.x * blockDim.x) {
        int r = row[e];
        int p = atomicAdd(&cursor[r], 1);
        colA[p] = col[e];
        valA[p] = val[e];
    }
}

// ============================ GEMM v2: 64 rows x 16 cols per wave ============================
// Out[n x C] = H[n x K] @ W[K x C] (+bias, relu). C/16 waves per block (uniform W cols
// per wave -> scalar W loads). h loaded as (possibly unaligned) float4.
template <int K, int C>
__global__ __launch_bounds__(64 * (C / 16))
void gemm2(const float* __restrict__ A1, int ld1, int split,
           const float* __restrict__ A2, int ld2,
           const float* __restrict__ W, const float* __restrict__ bias, int doRelu,
           float* __restrict__ Out, int n) {
    int lane  = threadIdx.x & 63;
    int cbase = __builtin_amdgcn_readfirstlane((threadIdx.x >> 6) * 16);
    int r  = blockIdx.x * 64 + lane;
    int rr = (r < n) ? r : (n - 1);
    const float* __restrict__ a1 = A1 + (size_t)rr * ld1;
    const float* __restrict__ a2 = A2 + (size_t)rr * ld2;
    float acc[16];
#pragma unroll
    for (int c = 0; c < 16; c++) acc[c] = 0.f;

#pragma unroll
    for (int k = 0; k < K; k += 4) {
        const float* p = (k < split) ? (a1 + k) : (a2 + (k - split));
        f4u h = *(const f4u*)p;
        const float* __restrict__ w = W + (size_t)k * C + cbase;
#pragma unroll
        for (int kk = 0; kk < 4; kk++) {
            float hv = h[kk];
#pragma unroll
            for (int c = 0; c < 16; c++) acc[c] = fmaf(hv, w[kk * C + c], acc[c]);
        }
    }

    if (r < n) {
        float* o = Out + (size_t)r * C + cbase;
#pragma unroll
        for (int c = 0; c < 16; c++) {
            float v = acc[c];
            if (bias) v += bias[cbase + c];
            if (doRelu) v = fmaxf(v, 0.f);
            o[c] = v;
        }
    }
}

// ============================ Aggregation v3 ============================
// 32-lane group per node. Per 32-edge chunk: coalesced load of 32 (col,val) pairs,
// broadcast via shfl, then independent row-gathers (lane reads 12B [C=96] or 8B [C=64]).
template <int C, bool DOBN>
__global__ __launch_bounds__(256)
void agg_kernel(const float* __restrict__ S, const int* __restrict__ offs,
                const int* __restrict__ colA, const float* __restrict__ valA,
                const float* __restrict__ cb, const float* __restrict__ bias,
                float* __restrict__ Hout, float* __restrict__ bsum,
                float* __restrict__ bsumsq, int n) {
    constexpr int LC = C / 32;           // floats per lane (3 or 2)
    int lane = threadIdx.x & 63;
    int lg   = lane & 31;                // lane in group
    int grp  = threadIdx.x >> 5;         // 8 groups per block
    int sh   = lane & 32;                // shfl base for this half-wave

    float cbr[LC], bir[LC];
#pragma unroll
    for (int a = 0; a < LC; a++) { cbr[a] = cb[LC * lg + a]; bir[a] = bias[LC * lg + a]; }

    float psum[LC], psq[LC];
#pragma unroll
    for (int a = 0; a < LC; a++) { psum[a] = 0.f; psq[a] = 0.f; }

    for (int node = blockIdx.x * 8 + grp; node < n; node += gridDim.x * 8) {
        int e0 = offs[node], e1 = offs[node + 1];
        float acc[LC];
#pragma unroll
        for (int a = 0; a < LC; a++) acc[a] = 0.f;
        float vsum = 0.f;

        for (int e = e0; e < e1; e += 32) {
            int   idx = e + lg;
            int   ce = (idx < e1) ? colA[idx] : 0;
            float ve = (idx < e1) ? valA[idx] : 0.f;
            int   cnt = min(32, e1 - e);
#pragma unroll 8
            for (int j = 0; j < cnt; j++) {
                int   c = __shfl(ce, sh + j);
                float v = __shfl(ve, sh + j);
                const float* srow = S + (size_t)c * C + LC * lg;
                if (LC == 3) {
                    f3u g = *(const f3u*)srow;
                    acc[0] = fmaf(v, g[0], acc[0]);
                    acc[1] = fmaf(v, g[1], acc[1]);
                    acc[2] = fmaf(v, g[2], acc[2]);
                } else {
                    f2u g = *(const f2u*)srow;
                    acc[0] = fmaf(v, g[0], acc[0]);
                    acc[1] = fmaf(v, g[1], acc[1]);
                }
                vsum += v;
            }
        }

        float* orow = Hout + (size_t)node * C + LC * lg;
        if (LC == 3) {
            f3u o;
#pragma unroll
            for (int a = 0; a < 3; a++) {
                float t = fmaxf(acc[a] + cbr[a] * vsum + bir[a], 0.f);
                o[a] = t;
                if (DOBN) { psum[a] += t; psq[a] += t * t; }
            }
            *(f3u*)orow = o;
        } else {
            f2u o;
#pragma unroll
            for (int a = 0; a < 2; a++) {
                float t = fmaxf(acc[a] + cbr[a] * vsum + bir[a], 0.f);
                o[a] = t;
                if (DOBN) { psum[a] += t; psq[a] += t * t; }
            }
            *(f2u*)orow = o;
        }
    }

    if (DOBN) {
        __shared__ float red[DOBN ? 8 * C : 1];
#pragma unroll
        for (int a = 0; a < LC; a++) red[grp * C + LC * lg + a] = psum[a];
        __syncthreads();
        if (threadIdx.x < C) {
            float s = 0.f;
            for (int g = 0; g < 8; g++) s += red[g * C + threadIdx.x];
            atomicAdd(&bsum[threadIdx.x], s);
        }
        __syncthreads();
#pragma unroll
        for (int a = 0; a < LC; a++) red[grp * C + LC * lg + a] = psq[a];
        __syncthreads();
        if (threadIdx.x < C) {
            float s = 0.f;
            for (int g = 0; g < 8; g++) s += red[g * C + threadIdx.x];
            atomicAdd(&bsumsq[threadIdx.x], s);
        }
    }
}

// ============================ BN fold ============================
template <int C>
__global__ __launch_bounds__(256)
void fold_kernel(const float* __restrict__ W, float* __restrict__ bsum,
                 float* __restrict__ bsumsq, float* __restrict__ Wf,
                 float* __restrict__ cb, int N) {
    __shared__ float mean[96], inv[96];
    int t = threadIdx.x;
    float rn = 1.0f / (float)N;
    if (t < 96) {
        float mu  = bsum[t] * rn;
        float var = bsumsq[t] * rn - mu * mu;
        mean[t] = mu;
        inv[t]  = rsqrtf(var + 1e-5f);
        bsum[t] = 0.f;
        bsumsq[t] = 0.f;
    }
    __syncthreads();
    for (int i = t; i < 96 * C; i += 256) {
        int k = i / C;
        Wf[i] = inv[k] * W[i];
    }
    if (t < C) {
        float s = 0.f;
        for (int k = 0; k < 96; k++) s += mean[k] * inv[k] * W[k * C + t];
        cb[t] = -s;
    }
}

// ============================ final dot (64->1) + global min ============================
__global__ __launch_bounds__(256)
void dot_min_kernel(const float* __restrict__ A, const float* __restrict__ M3w,
                    const float* __restrict__ M3b, float* __restrict__ m,
                    unsigned* __restrict__ gmin, int n) {
    int lane = threadIdx.x & 63;
    int wv   = threadIdx.x >> 6;
    float w  = M3w[lane];
    float b  = M3b[0];
    float lmin = 3.4e38f;
    int nw = gridDim.x * 4;
    for (int r = blockIdx.x * 4 + wv; r < n; r += nw) {
        float v = A[(size_t)r * 64 + lane] * w;
#pragma unroll
        for (int o = 32; o; o >>= 1) v += __shfl_down(v, o);
        if (lane == 0) {
            float mv = v + b;
            m[r] = mv;
            lmin = fminf(lmin, mv);
        }
    }
#pragma unroll
    for (int o = 32; o; o >>= 1) lmin = fminf(lmin, __shfl_down(lmin, o));
    __shared__ float sm[4];
    if (lane == 0) sm[wv] = lmin;
    __syncthreads();
    if (threadIdx.x == 0) {
        float mn = fminf(fminf(sm[0], sm[1]), fminf(sm[2], sm[3]));
        unsigned u = __float_as_uint(mn);
        unsigned key = (u >> 31) ? ~u : (u | 0x80000000u);
        atomicMin(gmin, key);
    }
}

__global__ void where_kernel(const float* __restrict__ x, float* __restrict__ m,
                             const unsigned* __restrict__ gmin, int n) {
    int i = blockIdx.x * blockDim.x + threadIdx.x;
    if (i < n) {
        unsigned k = *gmin;
        unsigned u = (k >> 31) ? (k ^ 0x80000000u) : ~k;
        float g = __uint_as_float(u);
        if (x[(size_t)i * XLD + 160] == 0.0f) m[i] = g;
    }
}

// ============================ exact radix select ============================
__device__ inline unsigned fkey(float f) {
    unsigned u = __float_as_uint(f);
    return (u >> 31) ? ~u : (u | 0x80000000u);
}

__global__ __launch_bounds__(1024)
void select_kernel(const float* __restrict__ m, int n, int kwant, float* __restrict__ thresh) {
    __shared__ unsigned hist[256];
    __shared__ unsigned sprefix;
    __shared__ int skk;
    int t = threadIdx.x;
    if (t == 0) { sprefix = 0u; skk = kwant; }
    for (int pass = 0; pass < 4; ++pass) {
        if (t < 256) hist[t] = 0u;
        __syncthreads();
        int shift = 24 - 8 * pass;
        unsigned pfx = sprefix;
        for (int i = t; i < n; i += 1024) {
            unsigned key = fkey(m[i]);
            bool ok = (pass == 0) || ((key >> (shift + 8)) == (pfx >> (shift + 8)));
            if (ok) atomicAdd(&hist[(key >> shift) & 255u], 1u);
        }
        __syncthreads();
        if (t == 0) {
            int cum = 0, kk = skk, chosen = 0;
            for (int b = 255; b >= 0; b--) {
                cum += (int)hist[b];
                if (cum >= kk) { chosen = b; kk -= (cum - (int)hist[b]); break; }
            }
            sprefix = pfx | ((unsigned)chosen << shift);
            skk = kk;
        }
        __syncthreads();
    }
    if (t == 0) {
        unsigned key = sprefix;
        unsigned u = (key >> 31) ? (key ^ 0x80000000u) : ~key;
        *thresh = __uint_as_float(u);
    }
}

__global__ void mask_kernel(const float* __restrict__ m, const float* __restrict__ thresh,
                            float* __restrict__ out, int n) {
    int i = blockIdx.x * blockDim.x + threadIdx.x;
    if (i < n) {
        float t = *thresh, v = m[i];
        out[i] = (v > t) ? v * (1.0f / v) : 0.0f;
    }
}

// ============================ launch ============================
extern "C" void kernel_launch(void* const* d_in, const int* in_sizes, int n_in,
                              void* d_out, int out_size, void* d_ws, size_t ws_size,
                              hipStream_t stream) {
    const float* x   = (const float*)d_in[0];
    const int*   row = (const int*)d_in[1];
    const int*   col = (const int*)d_in[2];
    const float* val = (const float*)d_in[3];
    const float* W1  = (const float*)d_in[4];
    const float* b1  = (const float*)d_in[5];
    const float* W2  = (const float*)d_in[6];
    const float* b2  = (const float*)d_in[7];
    const float* W3  = (const float*)d_in[8];
    const float* b3  = (const float*)d_in[9];
    const float* W4  = (const float*)d_in[10];
    const float* b4  = (const float*)d_in[11];
    const float* W5  = (const float*)d_in[12];
    const float* b5  = (const float*)d_in[13];
    const float* M1w = (const float*)d_in[14];
    const float* M1b = (const float*)d_in[15];
    const float* M2w = (const float*)d_in[16];
    const float* M2b = (const float*)d_in[17];
    const float* M3w = (const float*)d_in[18];
    const float* M3b = (const float*)d_in[19];

    const int n = in_sizes[0] / XLD;   // 50000
    const int E = in_sizes[1];         // 800000

    char* ws = (char*)d_ws;
    size_t off = 0;
    auto carve = [&](size_t bytes) -> void* {
        void* p = ws + off;
        off = (off + bytes + 255) & ~(size_t)255;
        return p;
    };
    int*      offs   = (int*)carve((size_t)(n + 1) * 4);
    int*      cursor = (int*)carve((size_t)n * 4);
    int*      bsums  = (int*)carve(256 * 4);
    int*      colA   = (int*)carve((size_t)E * 4);
    float*    valA   = (float*)carve((size_t)E * 4);
    float*    h      = (float*)carve((size_t)n * 96 * 4);
    float*    big    = (float*)carve((size_t)n * 128 * 4);
    float*    Wf     = (float*)carve(96 * 96 * 4);
    float*    stats  = (float*)carve(288 * 4);
    float*    cb     = (float*)carve(96 * 4);
    float*    m      = (float*)carve((size_t)n * 4);
    unsigned* gmin   = (unsigned*)carve(4);
    float*    thresh = (float*)carve(4);
    float* cb0    = stats;
    float* bsum   = stats + 96;
    float* bsumsq = stats + 192;

    hipMemsetAsync(cursor, 0, (size_t)n * 4, stream);
    hipMemsetAsync(stats, 0, 288 * 4, stream);
    hipMemsetAsync(gmin, 0xFF, 4, stream);

    // CSR build
    const int nb = (n + 255) / 256;
    hist_kernel<<<512, 256, 0, stream>>>(row, cursor, E);
    scan1_kernel<<<nb, 256, 0, stream>>>(cursor, offs, bsums, n);
    scan2_kernel<<<1, 256, 0, stream>>>(bsums, nb);
    scan3_kernel<<<nb, 256, 0, stream>>>(offs, cursor, bsums, n, E);
    scatter_kernel<<<512, 256, 0, stream>>>(row, col, val, cursor, colA, valA, E);

    const int gg = (n + 63) / 64;       // 782 row-tiles
    const int ga = 1024;                // grid-stride over nodes (8 groups/block)

    // Layer 1
    gemm2<128, 96><<<gg, 384, 0, stream>>>(x, XLD, 128, x, XLD, W1, nullptr, 0, big, n);
    agg_kernel<96, true><<<ga, 256, 0, stream>>>(big, offs, colA, valA, cb0, b1, h, bsum, bsumsq, n);

    // Layers 2-4
    fold_kernel<96><<<1, 256, 0, stream>>>(W2, bsum, bsumsq, Wf, cb, n);
    gemm2<96, 96><<<gg, 384, 0, stream>>>(h, 96, 96, h, 96, Wf, nullptr, 0, big, n);
    agg_kernel<96, true><<<ga, 256, 0, stream>>>(big, offs, colA, valA, cb, b2, h, bsum, bsumsq, n);

    fold_kernel<96><<<1, 256, 0, stream>>>(W3, bsum, bsumsq, Wf, cb, n);
    gemm2<96, 96><<<gg, 384, 0, stream>>>(h, 96, 96, h, 96, Wf, nullptr, 0, big, n);
    agg_kernel<96, true><<<ga, 256, 0, stream>>>(big, offs, colA, valA, cb, b3, h, bsum, bsumsq, n);

    fold_kernel<96><<<1, 256, 0, stream>>>(W4, bsum, bsumsq, Wf, cb, n);
    gemm2<96, 96><<<gg, 384, 0, stream>>>(h, 96, 96, h, 96, Wf, nullptr, 0, big, n);
    agg_kernel<96, true><<<ga, 256, 0, stream>>>(big, offs, colA, valA, cb, b4, h, bsum, bsumsq, n);

    // Layer 5 (96 -> 64, no BN after)
    fold_kernel<64><<<1, 256, 0, stream>>>(W5, bsum, bsumsq, Wf, cb, n);
    gemm2<96, 64><<<gg, 256, 0, stream>>>(h, 96, 96, h, 96, Wf, nullptr, 0, big, n);
    agg_kernel<64, false><<<ga, 256, 0, stream>>>(big, offs, colA, valA, cb, b5, h, bsum, bsumsq, n);

    // MLP
    gemm2<96, 128><<<gg, 512, 0, stream>>>(h, 64, 64, x + 128, XLD, M1w, M1b, 1, big, n);
    gemm2<128, 64><<<gg, 256, 0, stream>>>(big, 128, 128, big, 128, M2w, M2b, 1, h, n);

    // m = a2 @ M3w + M3b ; global min
    dot_min_kernel<<<256, 256, 0, stream>>>(h, M3w, M3b, m, gmin, n);

    // where(grp==0, min, m)
    where_kernel<<<(n + 255) / 256, 256, 0, stream>>>(x, m, gmin, n);

    // exact 71st-largest threshold
    select_kernel<<<1, 1024, 0, stream>>>(m, n, 71, thresh);

    // out = m>thresh ? 1 : 0 (as m * (1/m))
    mask_kernel<<<(n + 255) / 256, 256, 0, stream>>>(m, thresh, (float*)d_out, n);
}

// Round 5
// 890.738 us; speedup vs baseline: 2.4818x; 2.4818x over previous
//
#include <hip/hip_runtime.h>
#include <cstdint>
#include <cstddef>

#define XLD 161   // x row stride = NFEAT + EXTRA + 1

typedef float f4u __attribute__((ext_vector_type(4), aligned(4)));
typedef float f3u __attribute__((ext_vector_type(3), aligned(4)));

// ============================ CSR build ============================
__global__ void hist_kernel(const int* __restrict__ row, int* __restrict__ cnt, int E) {
    for (int e = blockIdx.x * blockDim.x + threadIdx.x; e < E; e += gridDim.x * blockDim.x)
        atomicAdd(&cnt[row[e]], 1);
}

__global__ __launch_bounds__(256)
void scan1_kernel(const int* __restrict__ cnt, int* __restrict__ offs,
                  int* __restrict__ bsums, int n) {
    int t = threadIdx.x;
    int gid = blockIdx.x * 256 + t;
    int v = (gid < n) ? cnt[gid] : 0;
    int x = v;
#pragma unroll
    for (int o = 1; o < 64; o <<= 1) { int y = __shfl_up(x, o); if ((t & 63) >= o) x += y; }
    __shared__ int ws[4];
    if ((t & 63) == 63) ws[t >> 6] = x;
    __syncthreads();
    int add = 0;
    for (int w = 0; w < (t >> 6); w++) add += ws[w];
    int incl = x + add;
    if (gid < n) offs[gid] = incl - v;
    if (t == 255) bsums[blockIdx.x] = incl;
}

__global__ __launch_bounds__(256)
void scan2_kernel(int* __restrict__ bsums, int nb) {
    int t = threadIdx.x;
    int v = (t < nb) ? bsums[t] : 0;
    int x = v;
#pragma unroll
    for (int o = 1; o < 64; o <<= 1) { int y = __shfl_up(x, o); if ((t & 63) >= o) x += y; }
    __shared__ int ws[4];
    if ((t & 63) == 63) ws[t >> 6] = x;
    __syncthreads();
    int add = 0;
    for (int w = 0; w < (t >> 6); w++) add += ws[w];
    if (t < nb) bsums[t] = x + add - v;
}

__global__ void scan3_kernel(int* __restrict__ offs, int* __restrict__ cursor,
                             const int* __restrict__ bsums, int n, int E) {
    int gid = blockIdx.x * 256 + threadIdx.x;
    if (gid < n) {
        int o = offs[gid] + bsums[blockIdx.x];
        offs[gid] = o;
        cursor[gid] = o;
    }
    if (gid == 0) offs[n] = E;
}

__global__ void scatter_kernel(const int* __restrict__ row, const int* __restrict__ col,
                               const float* __restrict__ val, int* __restrict__ cursor,
                               int* __restrict__ colA, float* __restrict__ valA, int E) {
    for (int e = blockIdx.x * blockDim.x + threadIdx.x; e < E; e += gridDim.x * blockDim.x) {
        int r = row[e];
        int p = atomicAdd(&cursor[r], 1);
        colA[p] = col[e];
        valA[p] = val[e];
    }
}

// ============================ Pure aggregation: Aout[i] = sum_e val * S[col_e] ============================
// 32-lane group per node; 32-edge chunks: coalesced (col,val) load, shfl broadcast,
// independent full-row gathers (lane reads LC*4 bytes of the row).
template <int LC, bool WVS>   // LC floats per lane; row width = 32*LC
__global__ __launch_bounds__(256)
void aggP(const float* __restrict__ S, int ldS, const int* __restrict__ offs,
          const int* __restrict__ colA, const float* __restrict__ valA,
          float* __restrict__ Aout, float* __restrict__ vout, int n) {
    int lane = threadIdx.x & 63;
    int lg   = lane & 31;
    int grp  = threadIdx.x >> 5;
    int sh   = lane & 32;

    for (int node = blockIdx.x * 8 + grp; node < n; node += gridDim.x * 8) {
        int e0 = offs[node], e1 = offs[node + 1];
        float acc[LC];
#pragma unroll
        for (int a = 0; a < LC; a++) acc[a] = 0.f;
        float vsum = 0.f;

        for (int e = e0; e < e1; e += 32) {
            int   idx = e + lg;
            int   ce = (idx < e1) ? colA[idx] : 0;
            float ve = (idx < e1) ? valA[idx] : 0.f;
            int   cnt = min(32, e1 - e);
#pragma unroll 8
            for (int j = 0; j < cnt; j++) {
                int   c = __shfl(ce, sh + j);
                float v = __shfl(ve, sh + j);
                const float* srow = S + (size_t)c * ldS + LC * lg;
                if (LC == 3) {
                    f3u g = *(const f3u*)srow;
                    acc[0] = fmaf(v, g[0], acc[0]);
                    acc[1] = fmaf(v, g[1], acc[1]);
                    acc[2] = fmaf(v, g[2], acc[2]);
                } else {
                    f4u g = *(const f4u*)srow;
                    acc[0] = fmaf(v, g[0], acc[0]);
                    acc[1] = fmaf(v, g[1], acc[1]);
                    acc[2] = fmaf(v, g[2], acc[2]);
                    acc[3] = fmaf(v, g[3], acc[3]);
                }
                vsum += v;
            }
        }

        float* orow = Aout + (size_t)node * (32 * LC) + LC * lg;
        if (LC == 3) {
            f3u o; o[0] = acc[0]; o[1] = acc[1]; o[2] = acc[2];
            *(f3u*)orow = o;
        } else {
            f4u o; o[0] = acc[0]; o[1] = acc[1]; o[2] = acc[2]; o[3] = acc[3];
            *(f4u*)orow = o;
        }
        if (WVS && lg == 0) vout[node] = vsum;
    }
}

// ============================ Tiled GEMM with fused epilogue ============================
// Out[n x C] = relu( A[n x K] @ W + vsum*cb + bias ), optional BN stats accumulation.
// A element k read from A1 (ld1) for k < split else A2 (ld2) at k-split.
// Block: 256 threads, 128-row tile, W fully in LDS, A staged in 16-k transposed chunks.
// Thread (tc = t&15, tr = t>>4) computes rows tr*8..+7, cols tc*CT..+CT-1.
template <int K, int C, bool DOBN, bool HASCB>
__global__ __launch_bounds__(256)
void gemmF(const float* __restrict__ A1, int ld1, int split,
           const float* __restrict__ A2, int ld2,
           const float* __restrict__ W, const float* __restrict__ bias,
           const float* __restrict__ cbv, const float* __restrict__ vsum,
           float* __restrict__ Out, float* __restrict__ bsum,
           float* __restrict__ bsumsq, int n) {
    constexpr int CT = C / 16;           // cols per thread (4, 6, or 8)
    __shared__ float Ws[K * C];
    __shared__ float At[16][132];        // [k][row], pad 132 (2-way max on writes)
    __shared__ float redS[DOBN ? C : 1];
    __shared__ float redQ[DOBN ? C : 1];

    int t  = threadIdx.x;
    int tc = t & 15, tr = t >> 4;
    int row0 = blockIdx.x * 128;

    // stage W (coalesced float4)
    for (int i = t * 4; i < K * C; i += 1024)
        *(float4*)&Ws[i] = *(const float4*)&W[i];
    if (DOBN && t < C) { redS[t] = 0.f; redQ[t] = 0.f; }

    // staging role: thread stages row srow, 8 k's starting at kh
    int srow = t >> 1;
    int gr = row0 + srow; if (gr >= n) gr = n - 1;
    int kh = (t & 1) * 8;

    float acc[8][CT];
#pragma unroll
    for (int i = 0; i < 8; i++)
#pragma unroll
        for (int c = 0; c < CT; c++) acc[i][c] = 0.f;

    for (int kb = 0; kb < K; kb += 16) {
        __syncthreads();
#pragma unroll
        for (int q = 0; q < 2; q++) {
            int kg = kb + kh + q * 4;
            const float* src = (kg < split) ? (A1 + (size_t)gr * ld1 + kg)
                                            : (A2 + (size_t)gr * ld2 + (kg - split));
            f4u v = *(const f4u*)src;
#pragma unroll
            for (int e = 0; e < 4; e++) At[kh + q * 4 + e][srow] = v[e];
        }
        __syncthreads();
#pragma unroll
        for (int kk = 0; kk < 16; kk++) {
            float av[8];
            *(float4*)&av[0] = *(const float4*)&At[kk][tr * 8];
            *(float4*)&av[4] = *(const float4*)&At[kk][tr * 8 + 4];
            float wv[CT];
#pragma unroll
            for (int c = 0; c < CT; c++) wv[c] = Ws[(kb + kk) * C + tc * CT + c];
#pragma unroll
            for (int i = 0; i < 8; i++)
#pragma unroll
                for (int c = 0; c < CT; c++) acc[i][c] = fmaf(av[i], wv[c], acc[i][c]);
        }
    }

    // epilogue
    float bb[CT], cc[CT];
#pragma unroll
    for (int c = 0; c < CT; c++) {
        bb[c] = bias[tc * CT + c];
        cc[c] = HASCB ? cbv[tc * CT + c] : 0.f;
    }
    float ps[CT], pq[CT];
#pragma unroll
    for (int c = 0; c < CT; c++) { ps[c] = 0.f; pq[c] = 0.f; }

#pragma unroll
    for (int i = 0; i < 8; i++) {
        int r = row0 + tr * 8 + i;
        if (r < n) {
            float vs = HASCB ? vsum[r] : 0.f;
            float* o = Out + (size_t)r * C + tc * CT;
#pragma unroll
            for (int c = 0; c < CT; c++) {
                float v = acc[i][c] + vs * cc[c] + bb[c];
                v = fmaxf(v, 0.f);
                o[c] = v;
                if (DOBN) { ps[c] += v; pq[c] += v * v; }
            }
        }
    }
    if (DOBN) {
#pragma unroll
        for (int c = 0; c < CT; c++) {
            atomicAdd(&redS[tc * CT + c], ps[c]);
            atomicAdd(&redQ[tc * CT + c], pq[c]);
        }
        __syncthreads();
        if (t < C) {
            atomicAdd(&bsum[t], redS[t]);
            atomicAdd(&bsumsq[t], redQ[t]);
        }
    }
}

// ============================ BN fold: Wf = inv*W, cb = -sum(mean*inv*W) ============================
template <int C>
__global__ __launch_bounds__(256)
void fold_kernel(const float* __restrict__ W, float* __restrict__ bsum,
                 float* __restrict__ bsumsq, float* __restrict__ Wf,
                 float* __restrict__ cb, int N) {
    __shared__ float mean[96], inv[96];
    int t = threadIdx.x;
    float rn = 1.0f / (float)N;
    if (t < 96) {
        float mu  = bsum[t] * rn;
        float var = bsumsq[t] * rn - mu * mu;
        mean[t] = mu;
        inv[t]  = rsqrtf(var + 1e-5f);
        bsum[t] = 0.f;
        bsumsq[t] = 0.f;
    }
    __syncthreads();
    for (int i = t; i < 96 * C; i += 256) {
        int k = i / C;
        Wf[i] = inv[k] * W[i];
    }
    if (t < C) {
        float s = 0.f;
        for (int k = 0; k < 96; k++) s += mean[k] * inv[k] * W[k * C + t];
        cb[t] = -s;
    }
}

// ============================ final dot (64->1) + global min ============================
__global__ __launch_bounds__(256)
void dot_min_kernel(const float* __restrict__ A, const float* __restrict__ M3w,
                    const float* __restrict__ M3b, float* __restrict__ m,
                    unsigned* __restrict__ gmin, int n) {
    int lane = threadIdx.x & 63;
    int wv   = threadIdx.x >> 6;
    float w  = M3w[lane];
    float b  = M3b[0];
    float lmin = 3.4e38f;
    int nw = gridDim.x * 4;
    for (int r = blockIdx.x * 4 + wv; r < n; r += nw) {
        float v = A[(size_t)r * 64 + lane] * w;
#pragma unroll
        for (int o = 32; o; o >>= 1) v += __shfl_down(v, o);
        if (lane == 0) {
            float mv = v + b;
            m[r] = mv;
            lmin = fminf(lmin, mv);
        }
    }
#pragma unroll
    for (int o = 32; o; o >>= 1) lmin = fminf(lmin, __shfl_down(lmin, o));
    __shared__ float sm[4];
    if (lane == 0) sm[wv] = lmin;
    __syncthreads();
    if (threadIdx.x == 0) {
        float mn = fminf(fminf(sm[0], sm[1]), fminf(sm[2], sm[3]));
        unsigned u = __float_as_uint(mn);
        unsigned key = (u >> 31) ? ~u : (u | 0x80000000u);
        atomicMin(gmin, key);
    }
}

__global__ void where_kernel(const float* __restrict__ x, float* __restrict__ m,
                             const unsigned* __restrict__ gmin, int n) {
    int i = blockIdx.x * blockDim.x + threadIdx.x;
    if (i < n) {
        unsigned k = *gmin;
        unsigned u = (k >> 31) ? (k ^ 0x80000000u) : ~k;
        float g = __uint_as_float(u);
        if (x[(size_t)i * XLD + 160] == 0.0f) m[i] = g;
    }
}

// ============================ exact radix select ============================
__device__ inline unsigned fkey(float f) {
    unsigned u = __float_as_uint(f);
    return (u >> 31) ? ~u : (u | 0x80000000u);
}

__global__ __launch_bounds__(1024)
void select_kernel(const float* __restrict__ m, int n, int kwant, float* __restrict__ thresh) {
    __shared__ unsigned hist[256];
    __shared__ unsigned sprefix;
    __shared__ int skk;
    int t = threadIdx.x;
    if (t == 0) { sprefix = 0u; skk = kwant; }
    for (int pass = 0; pass < 4; ++pass) {
        if (t < 256) hist[t] = 0u;
        __syncthreads();
        int shift = 24 - 8 * pass;
        unsigned pfx = sprefix;
        for (int i = t; i < n; i += 1024) {
            unsigned key = fkey(m[i]);
            bool ok = (pass == 0) || ((key >> (shift + 8)) == (pfx >> (shift + 8)));
            if (ok) atomicAdd(&hist[(key >> shift) & 255u], 1u);
        }
        __syncthreads();
        if (t == 0) {
            int cum = 0, kk = skk, chosen = 0;
            for (int b = 255; b >= 0; b--) {
                cum += (int)hist[b];
                if (cum >= kk) { chosen = b; kk -= (cum - (int)hist[b]); break; }
            }
            sprefix = pfx | ((unsigned)chosen << shift);
            skk = kk;
        }
        __syncthreads();
    }
    if (t == 0) {
        unsigned key = sprefix;
        unsigned u = (key >> 31) ? (key ^ 0x80000000u) : ~key;
        *thresh = __uint_as_float(u);
    }
}

__global__ void mask_kernel(const float* __restrict__ m, const float* __restrict__ thresh,
                            float* __restrict__ out, int n) {
    int i = blockIdx.x * blockDim.x + threadIdx.x;
    if (i < n) {
        float t = *thresh, v = m[i];
        out[i] = (v > t) ? v * (1.0f / v) : 0.0f;
    }
}

// ============================ launch ============================
extern "C" void kernel_launch(void* const* d_in, const int* in_sizes, int n_in,
                              void* d_out, int out_size, void* d_ws, size_t ws_size,
                              hipStream_t stream) {
    const float* x   = (const float*)d_in[0];
    const int*   row = (const int*)d_in[1];
    const int*   col = (const int*)d_in[2];
    const float* val = (const float*)d_in[3];
    const float* W1  = (const float*)d_in[4];
    const float* b1  = (const float*)d_in[5];
    const float* W2  = (const float*)d_in[6];
    const float* b2  = (const float*)d_in[7];
    const float* W3  = (const float*)d_in[8];
    const float* b3  = (const float*)d_in[9];
    const float* W4  = (const float*)d_in[10];
    const float* b4  = (const float*)d_in[11];
    const float* W5  = (const float*)d_in[12];
    const float* b5  = (const float*)d_in[13];
    const float* M1w = (const float*)d_in[14];
    const float* M1b = (const float*)d_in[15];
    const float* M2w = (const float*)d_in[16];
    const float* M2b = (const float*)d_in[17];
    const float* M3w = (const float*)d_in[18];
    const float* M3b = (const float*)d_in[19];

    const int n = in_sizes[0] / XLD;   // 50000
    const int E = in_sizes[1];         // 800000

    char* ws = (char*)d_ws;
    size_t off = 0;
    auto carve = [&](size_t bytes) -> void* {
        void* p = ws + off;
        off = (off + bytes + 255) & ~(size_t)255;
        return p;
    };
    int*      offs   = (int*)carve((size_t)(n + 1) * 4);
    int*      cursor = (int*)carve((size_t)n * 4);
    int*      bsums  = (int*)carve(256 * 4);
    int*      colA   = (int*)carve((size_t)E * 4);
    float*    valA   = (float*)carve((size_t)E * 4);
    float*    h      = (float*)carve((size_t)n * 96 * 4);   // activations (h5/m-input live here)
    float*    big    = (float*)carve((size_t)n * 128 * 4);  // aggX / aggH / MLP a1
    float*    Wf     = (float*)carve(96 * 96 * 4);
    float*    stats  = (float*)carve(192 * 4);              // bsum | bsumsq
    float*    cb     = (float*)carve(96 * 4);
    float*    vsum   = (float*)carve((size_t)n * 4);
    float*    m      = (float*)carve((size_t)n * 4);
    unsigned* gmin   = (unsigned*)carve(4);
    float*    thresh = (float*)carve(4);
    float* bsum   = stats;
    float* bsumsq = stats + 96;

    hipMemsetAsync(cursor, 0, (size_t)n * 4, stream);
    hipMemsetAsync(stats, 0, 192 * 4, stream);
    hipMemsetAsync(gmin, 0xFF, 4, stream);

    // CSR build
    const int nb = (n + 255) / 256;
    hist_kernel<<<512, 256, 0, stream>>>(row, cursor, E);
    scan1_kernel<<<nb, 256, 0, stream>>>(cursor, offs, bsums, n);
    scan2_kernel<<<1, 256, 0, stream>>>(bsums, nb);
    scan3_kernel<<<nb, 256, 0, stream>>>(offs, cursor, bsums, n, E);
    scatter_kernel<<<512, 256, 0, stream>>>(row, col, val, cursor, colA, valA, E);

    const int gB = (n + 127) / 128;     // gemmF row tiles
    const int ga = 1024;                // agg blocks (8 groups each, grid-stride)

    // Layer 1: aggX = agg(x[:, :128]) (+vsum once); h1 = relu(aggX@W1 + b1), BN stats
    aggP<4, true><<<ga, 256, 0, stream>>>(x, XLD, offs, colA, valA, big, vsum, n);
    gemmF<128, 96, true, false><<<gB, 256, 0, stream>>>(big, 128, 128, big, 128,
        W1, b1, nullptr, nullptr, h, bsum, bsumsq, n);

    // Layers 2-4: fold BN into W; aggH = agg(h); h = relu(aggH@W' + vsum*cb + b), BN stats
    fold_kernel<96><<<1, 256, 0, stream>>>(W2, bsum, bsumsq, Wf, cb, n);
    aggP<3, false><<<ga, 256, 0, stream>>>(h, 96, offs, colA, valA, big, nullptr, n);
    gemmF<96, 96, true, true><<<gB, 256, 0, stream>>>(big, 96, 96, big, 96,
        Wf, b2, cb, vsum, h, bsum, bsumsq, n);

    fold_kernel<96><<<1, 256, 0, stream>>>(W3, bsum, bsumsq, Wf, cb, n);
    aggP<3, false><<<ga, 256, 0, stream>>>(h, 96, offs, colA, valA, big, nullptr, n);
    gemmF<96, 96, true, true><<<gB, 256, 0, stream>>>(big, 96, 96, big, 96,
        Wf, b3, cb, vsum, h, bsum, bsumsq, n);

    fold_kernel<96><<<1, 256, 0, stream>>>(W4, bsum, bsumsq, Wf, cb, n);
    aggP<3, false><<<ga, 256, 0, stream>>>(h, 96, offs, colA, valA, big, nullptr, n);
    gemmF<96, 96, true, true><<<gB, 256, 0, stream>>>(big, 96, 96, big, 96,
        Wf, b4, cb, vsum, h, bsum, bsumsq, n);

    // Layer 5: fold; aggH = agg(h4); h5 = relu(aggH@W5' + vsum*cb + b5) (no BN stats)
    fold_kernel<64><<<1, 256, 0, stream>>>(W5, bsum, bsumsq, Wf, cb, n);
    aggP<3, false><<<ga, 256, 0, stream>>>(h, 96, offs, colA, valA, big, nullptr, n);
    gemmF<96, 64, false, true><<<gB, 256, 0, stream>>>(big, 96, 96, big, 96,
        Wf, b5, cb, vsum, h, bsum, bsumsq, n);

    // MLP: a1 = relu([h5 | x[:,128:160]] @ M1w + M1b); a2 = relu(a1@M2w + M2b)
    gemmF<96, 128, false, false><<<gB, 256, 0, stream>>>(h, 64, 64, x + 128, XLD,
        M1w, M1b, nullptr, nullptr, big, bsum, bsumsq, n);
    gemmF<128, 64, false, false><<<gB, 256, 0, stream>>>(big, 128, 128, big, 128,
        M2w, M2b, nullptr, nullptr, h, bsum, bsumsq, n);

    // m = a2 @ M3w + M3b ; global min
    dot_min_kernel<<<256, 256, 0, stream>>>(h, M3w, M3b, m, gmin, n);

    // where(grp==0, min, m)
    where_kernel<<<(n + 255) / 256, 256, 0, stream>>>(x, m, gmin, n);

    // exact 71st-largest threshold
    select_kernel<<<1, 1024, 0, stream>>>(m, n, 71, thresh);

    // out = m>thresh ? m*(1/m) : 0
    mask_kernel<<<(n + 255) / 256, 256, 0, stream>>>(m, thresh, (float*)d_out, n);
}

// Round 6
// 824.232 us; speedup vs baseline: 2.6820x; 1.0807x over previous
//
#include <hip/hip_runtime.h>
#include <cstdint>
#include <cstddef>

#define XLD 161   // x row stride = NFEAT + EXTRA + 1

typedef float f4u __attribute__((ext_vector_type(4), aligned(4)));  // unaligned-tolerant
typedef float f4a __attribute__((ext_vector_type(4)));              // 16B-aligned
typedef float f3u __attribute__((ext_vector_type(3), aligned(4)));

// ============================ CSR build ============================
__global__ void hist_kernel(const int* __restrict__ row, int* __restrict__ cnt, int E) {
    for (int e = blockIdx.x * blockDim.x + threadIdx.x; e < E; e += gridDim.x * blockDim.x)
        atomicAdd(&cnt[row[e]], 1);
}

__global__ __launch_bounds__(256)
void scan1_kernel(const int* __restrict__ cnt, int* __restrict__ offs,
                  int* __restrict__ bsums, int n) {
    int t = threadIdx.x;
    int gid = blockIdx.x * 256 + t;
    int v = (gid < n) ? cnt[gid] : 0;
    int x = v;
#pragma unroll
    for (int o = 1; o < 64; o <<= 1) { int y = __shfl_up(x, o); if ((t & 63) >= o) x += y; }
    __shared__ int ws[4];
    if ((t & 63) == 63) ws[t >> 6] = x;
    __syncthreads();
    int add = 0;
    for (int w = 0; w < (t >> 6); w++) add += ws[w];
    int incl = x + add;
    if (gid < n) offs[gid] = incl - v;
    if (t == 255) bsums[blockIdx.x] = incl;
}

__global__ __launch_bounds__(256)
void scan2_kernel(int* __restrict__ bsums, int nb) {
    int t = threadIdx.x;
    int v = (t < nb) ? bsums[t] : 0;
    int x = v;
#pragma unroll
    for (int o = 1; o < 64; o <<= 1) { int y = __shfl_up(x, o); if ((t & 63) >= o) x += y; }
    __shared__ int ws[4];
    if ((t & 63) == 63) ws[t >> 6] = x;
    __syncthreads();
    int add = 0;
    for (int w = 0; w < (t >> 6); w++) add += ws[w];
    if (t < nb) bsums[t] = x + add - v;
}

__global__ void scan3_kernel(int* __restrict__ offs, int* __restrict__ cursor,
                             const int* __restrict__ bsums, int n, int E) {
    int gid = blockIdx.x * 256 + threadIdx.x;
    if (gid < n) {
        int o = offs[gid] + bsums[blockIdx.x];
        offs[gid] = o;
        cursor[gid] = o;
    }
    if (gid == 0) offs[n] = E;
}

__global__ void scatter_kernel(const int* __restrict__ row, const int* __restrict__ col,
                               const float* __restrict__ val, int* __restrict__ cursor,
                               int* __restrict__ colA, float* __restrict__ valA, int E) {
    for (int e = blockIdx.x * blockDim.x + threadIdx.x; e < E; e += gridDim.x * blockDim.x) {
        int r = row[e];
        int p = atomicAdd(&cursor[r], 1);
        colA[p] = col[e];
        valA[p] = val[e];
    }
}

// ============================ Pure aggregation ============================
template <int LC, bool WVS>   // LC floats per lane; row width = 32*LC
__global__ __launch_bounds__(256)
void aggP(const float* __restrict__ S, int ldS, const int* __restrict__ offs,
          const int* __restrict__ colA, const float* __restrict__ valA,
          float* __restrict__ Aout, float* __restrict__ vout, int n) {
    int lane = threadIdx.x & 63;
    int lg   = lane & 31;
    int grp  = threadIdx.x >> 5;
    int sh   = lane & 32;

    for (int node = blockIdx.x * 8 + grp; node < n; node += gridDim.x * 8) {
        int e0 = offs[node], e1 = offs[node + 1];
        float acc[LC];
#pragma unroll
        for (int a = 0; a < LC; a++) acc[a] = 0.f;
        float vsum = 0.f;

        for (int e = e0; e < e1; e += 32) {
            int   idx = e + lg;
            int   ce = (idx < e1) ? colA[idx] : 0;
            float ve = (idx < e1) ? valA[idx] : 0.f;
            int   cnt = min(32, e1 - e);
#pragma unroll 8
            for (int j = 0; j < cnt; j++) {
                int   c = __shfl(ce, sh + j);
                float v = __shfl(ve, sh + j);
                const float* srow = S + (size_t)c * ldS + LC * lg;
                if (LC == 3) {
                    f3u g = *(const f3u*)srow;
                    acc[0] = fmaf(v, g[0], acc[0]);
                    acc[1] = fmaf(v, g[1], acc[1]);
                    acc[2] = fmaf(v, g[2], acc[2]);
                } else {
                    f4u g = *(const f4u*)srow;
                    acc[0] = fmaf(v, g[0], acc[0]);
                    acc[1] = fmaf(v, g[1], acc[1]);
                    acc[2] = fmaf(v, g[2], acc[2]);
                    acc[3] = fmaf(v, g[3], acc[3]);
                }
                vsum += v;
            }
        }

        float* orow = Aout + (size_t)node * (32 * LC) + LC * lg;
        if (LC == 3) {
            f3u o; o[0] = acc[0]; o[1] = acc[1]; o[2] = acc[2];
            *(f3u*)orow = o;
        } else {
            f4u o; o[0] = acc[0]; o[1] = acc[1]; o[2] = acc[2]; o[3] = acc[3];
            *(f4u*)orow = o;
        }
        if (WVS && lg == 0) vout[node] = vsum;
    }
}

// ============================ Tiled GEMM v2: 64-row tile, chunked W, low LDS ============================
// Out[n x C] = relu( A[n x K] @ W + vsum*cb + bias ), optional BN stats.
// 256 threads: tc = t&15 owns CT=C/16 cols, tr = t>>4 owns 4 rows.
template <int CT>
__device__ inline void ldw(const float* p, float* wv) {
    if constexpr (CT == 4) { *(f4a*)wv = *(const f4a*)p; }
    else if constexpr (CT == 6) { *(f3u*)wv = *(const f3u*)p; *(f3u*)(wv + 3) = *(const f3u*)(p + 3); }
    else { *(f4a*)wv = *(const f4a*)p; *(f4a*)(wv + 4) = *(const f4a*)(p + 4); }
}

template <int K, int C, bool DOBN, bool HASCB>
__global__ __launch_bounds__(256)
void gemmF(const float* __restrict__ A1, int ld1, int split,
           const float* __restrict__ A2, int ld2,
           const float* __restrict__ W, const float* __restrict__ bias,
           const float* __restrict__ cbv, const float* __restrict__ vsum,
           float* __restrict__ Out, float* __restrict__ bsum,
           float* __restrict__ bsumsq, int n) {
    constexpr int CT = C / 16;           // 4, 6, or 8
    __shared__ float Wc[16 * C];         // current 16-k chunk of W
    __shared__ float At[16][68];         // [k][row]
    __shared__ float redS[DOBN ? C : 1];
    __shared__ float redQ[DOBN ? C : 1];

    int t  = threadIdx.x;
    int tc = t & 15, tr = t >> 4;
    int row0 = blockIdx.x * 64;

    if (DOBN && t < C) { redS[t] = 0.f; redQ[t] = 0.f; }

    // staging role: thread stages row srow, 4 k's at kh
    int srow = t >> 2;
    int gr = row0 + srow; if (gr >= n) gr = n - 1;
    int kh = (t & 3) * 4;

    float acc[4][CT];
#pragma unroll
    for (int i = 0; i < 4; i++)
#pragma unroll
        for (int c = 0; c < CT; c++) acc[i][c] = 0.f;

    for (int kb = 0; kb < K; kb += 16) {
        __syncthreads();
        // stage W chunk (coalesced float4)
        for (int i = t * 4; i < 16 * C; i += 1024)
            *(f4a*)&Wc[i] = *(const f4u*)&W[(size_t)kb * C + i];
        // stage A chunk (transposed)
        {
            int kg = kb + kh;
            const float* src = (kg < split) ? (A1 + (size_t)gr * ld1 + kg)
                                            : (A2 + (size_t)gr * ld2 + (kg - split));
            f4u v = *(const f4u*)src;
#pragma unroll
            for (int e = 0; e < 4; e++) At[kh + e][srow] = v[e];
        }
        __syncthreads();
#pragma unroll
        for (int kk = 0; kk < 16; kk++) {
            f4a av = *(const f4a*)&At[kk][tr * 4];
            float wv[CT];
            ldw<CT>(&Wc[kk * C + tc * CT], wv);
#pragma unroll
            for (int i = 0; i < 4; i++)
#pragma unroll
                for (int c = 0; c < CT; c++) acc[i][c] = fmaf(av[i], wv[c], acc[i][c]);
        }
    }

    // epilogue
    float bb[CT], cc[CT];
#pragma unroll
    for (int c = 0; c < CT; c++) {
        bb[c] = bias[tc * CT + c];
        cc[c] = HASCB ? cbv[tc * CT + c] : 0.f;
    }
    float ps[CT], pq[CT];
#pragma unroll
    for (int c = 0; c < CT; c++) { ps[c] = 0.f; pq[c] = 0.f; }

#pragma unroll
    for (int i = 0; i < 4; i++) {
        int r = row0 + tr * 4 + i;
        if (r < n) {
            float vs = HASCB ? vsum[r] : 0.f;
            float* o = Out + (size_t)r * C + tc * CT;
#pragma unroll
            for (int c = 0; c < CT; c++) {
                float v = acc[i][c] + vs * cc[c] + bb[c];
                v = fmaxf(v, 0.f);
                o[c] = v;
                if (DOBN) { ps[c] += v; pq[c] += v * v; }
            }
        }
    }
    if (DOBN) {
        // wave-level reduce across tr (lanes sharing tc): xor 16, 32
#pragma unroll
        for (int c = 0; c < CT; c++) {
            ps[c] += __shfl_xor(ps[c], 16);
            ps[c] += __shfl_xor(ps[c], 32);
            pq[c] += __shfl_xor(pq[c], 16);
            pq[c] += __shfl_xor(pq[c], 32);
        }
        if ((t & 48) == 0) {   // one lane per tc per wave
#pragma unroll
            for (int c = 0; c < CT; c++) {
                atomicAdd(&redS[tc * CT + c], ps[c]);
                atomicAdd(&redQ[tc * CT + c], pq[c]);
            }
        }
        __syncthreads();
        if (t < C) {
            atomicAdd(&bsum[t], redS[t]);
            atomicAdd(&bsumsq[t], redQ[t]);
        }
    }
}

// ============================ BN fold ============================
template <int C>
__global__ __launch_bounds__(256)
void fold_kernel(const float* __restrict__ W, float* __restrict__ bsum,
                 float* __restrict__ bsumsq, float* __restrict__ Wf,
                 float* __restrict__ cb, int N) {
    __shared__ float mean[96], inv[96];
    int t = threadIdx.x;
    float rn = 1.0f / (float)N;
    if (t < 96) {
        float mu  = bsum[t] * rn;
        float var = bsumsq[t] * rn - mu * mu;
        mean[t] = mu;
        inv[t]  = rsqrtf(var + 1e-5f);
        bsum[t] = 0.f;
        bsumsq[t] = 0.f;
    }
    __syncthreads();
    for (int i = t; i < 96 * C; i += 256) {
        int k = i / C;
        Wf[i] = inv[k] * W[i];
    }
    if (t < C) {
        float s = 0.f;
        for (int k = 0; k < 96; k++) s += mean[k] * inv[k] * W[k * C + t];
        cb[t] = -s;
    }
}

// ============================ final dot (64->1) + global min ============================
__global__ __launch_bounds__(256)
void dot_min_kernel(const float* __restrict__ A, const float* __restrict__ M3w,
                    const float* __restrict__ M3b, float* __restrict__ m,
                    unsigned* __restrict__ gmin, int n) {
    int lane = threadIdx.x & 63;
    int wv   = threadIdx.x >> 6;
    float w  = M3w[lane];
    float b  = M3b[0];
    float lmin = 3.4e38f;
    int nw = gridDim.x * 4;
    for (int r = blockIdx.x * 4 + wv; r < n; r += nw) {
        float v = A[(size_t)r * 64 + lane] * w;
#pragma unroll
        for (int o = 32; o; o >>= 1) v += __shfl_down(v, o);
        if (lane == 0) {
            float mv = v + b;
            m[r] = mv;
            lmin = fminf(lmin, mv);
        }
    }
#pragma unroll
    for (int o = 32; o; o >>= 1) lmin = fminf(lmin, __shfl_down(lmin, o));
    __shared__ float sm[4];
    if (lane == 0) sm[wv] = lmin;
    __syncthreads();
    if (threadIdx.x == 0) {
        float mn = fminf(fminf(sm[0], sm[1]), fminf(sm[2], sm[3]));
        unsigned u = __float_as_uint(mn);
        unsigned key = (u >> 31) ? ~u : (u | 0x80000000u);
        atomicMin(gmin, key);
    }
}

__global__ void where_kernel(const float* __restrict__ x, float* __restrict__ m,
                             const unsigned* __restrict__ gmin, int n) {
    int i = blockIdx.x * blockDim.x + threadIdx.x;
    if (i < n) {
        unsigned k = *gmin;
        unsigned u = (k >> 31) ? (k ^ 0x80000000u) : ~k;
        float g = __uint_as_float(u);
        if (x[(size_t)i * XLD + 160] == 0.0f) m[i] = g;
    }
}

// ============================ exact radix select ============================
__device__ inline unsigned fkey(float f) {
    unsigned u = __float_as_uint(f);
    return (u >> 31) ? ~u : (u | 0x80000000u);
}

__global__ __launch_bounds__(1024)
void select_kernel(const float* __restrict__ m, int n, int kwant, float* __restrict__ thresh) {
    __shared__ unsigned hist[256];
    __shared__ unsigned sprefix;
    __shared__ int skk;
    int t = threadIdx.x;
    if (t == 0) { sprefix = 0u; skk = kwant; }
    for (int pass = 0; pass < 4; ++pass) {
        if (t < 256) hist[t] = 0u;
        __syncthreads();
        int shift = 24 - 8 * pass;
        unsigned pfx = sprefix;
        for (int i = t; i < n; i += 1024) {
            unsigned key = fkey(m[i]);
            bool ok = (pass == 0) || ((key >> (shift + 8)) == (pfx >> (shift + 8)));
            if (ok) atomicAdd(&hist[(key >> shift) & 255u], 1u);
        }
        __syncthreads();
        if (t == 0) {
            int cum = 0, kk = skk, chosen = 0;
            for (int b = 255; b >= 0; b--) {
                cum += (int)hist[b];
                if (cum >= kk) { chosen = b; kk -= (cum - (int)hist[b]); break; }
            }
            sprefix = pfx | ((unsigned)chosen << shift);
            skk = kk;
        }
        __syncthreads();
    }
    if (t == 0) {
        unsigned key = sprefix;
        unsigned u = (key >> 31) ? (key ^ 0x80000000u) : ~key;
        *thresh = __uint_as_float(u);
    }
}

__global__ void mask_kernel(const float* __restrict__ m, const float* __restrict__ thresh,
                            float* __restrict__ out, int n) {
    int i = blockIdx.x * blockDim.x + threadIdx.x;
    if (i < n) {
        float t = *thresh, v = m[i];
        out[i] = (v > t) ? v * (1.0f / v) : 0.0f;
    }
}

// ============================ launch ============================
extern "C" void kernel_launch(void* const* d_in, const int* in_sizes, int n_in,
                              void* d_out, int out_size, void* d_ws, size_t ws_size,
                              hipStream_t stream) {
    const float* x   = (const float*)d_in[0];
    const int*   row = (const int*)d_in[1];
    const int*   col = (const int*)d_in[2];
    const float* val = (const float*)d_in[3];
    const float* W1  = (const float*)d_in[4];
    const float* b1  = (const float*)d_in[5];
    const float* W2  = (const float*)d_in[6];
    const float* b2  = (const float*)d_in[7];
    const float* W3  = (const float*)d_in[8];
    const float* b3  = (const float*)d_in[9];
    const float* W4  = (const float*)d_in[10];
    const float* b4  = (const float*)d_in[11];
    const float* W5  = (const float*)d_in[12];
    const float* b5  = (const float*)d_in[13];
    const float* M1w = (const float*)d_in[14];
    const float* M1b = (const float*)d_in[15];
    const float* M2w = (const float*)d_in[16];
    const float* M2b = (const float*)d_in[17];
    const float* M3w = (const float*)d_in[18];
    const float* M3b = (const float*)d_in[19];

    const int n = in_sizes[0] / XLD;   // 50000
    const int E = in_sizes[1];         // 800000

    char* ws = (char*)d_ws;
    size_t off = 0;
    auto carve = [&](size_t bytes) -> void* {
        void* p = ws + off;
        off = (off + bytes + 255) & ~(size_t)255;
        return p;
    };
    int*      offs   = (int*)carve((size_t)(n + 1) * 4);
    int*      cursor = (int*)carve((size_t)n * 4);
    int*      bsums  = (int*)carve(256 * 4);
    int*      colA   = (int*)carve((size_t)E * 4);
    float*    valA   = (float*)carve((size_t)E * 4);
    float*    h      = (float*)carve((size_t)n * 96 * 4);
    float*    big    = (float*)carve((size_t)n * 128 * 4);
    float*    Wf     = (float*)carve(96 * 96 * 4);
    float*    stats  = (float*)carve(192 * 4);
    float*    cb     = (float*)carve(96 * 4);
    float*    vsum   = (float*)carve((size_t)n * 4);
    float*    m      = (float*)carve((size_t)n * 4);
    unsigned* gmin   = (unsigned*)carve(4);
    float*    thresh = (float*)carve(4);
    float* bsum   = stats;
    float* bsumsq = stats + 96;

    hipMemsetAsync(cursor, 0, (size_t)n * 4, stream);
    hipMemsetAsync(stats, 0, 192 * 4, stream);
    hipMemsetAsync(gmin, 0xFF, 4, stream);

    // CSR build
    const int nb = (n + 255) / 256;
    hist_kernel<<<512, 256, 0, stream>>>(row, cursor, E);
    scan1_kernel<<<nb, 256, 0, stream>>>(cursor, offs, bsums, n);
    scan2_kernel<<<1, 256, 0, stream>>>(bsums, nb);
    scan3_kernel<<<nb, 256, 0, stream>>>(offs, cursor, bsums, n, E);
    scatter_kernel<<<512, 256, 0, stream>>>(row, col, val, cursor, colA, valA, E);

    const int gB = (n + 63) / 64;       // gemmF row tiles (782)
    const int ga = 3072;                // agg blocks (grid-stride)

    // Layer 1: aggX = agg(x[:, :128]) (+vsum once); h1 = relu(aggX@W1 + b1), BN stats
    aggP<4, true><<<ga, 256, 0, stream>>>(x, XLD, offs, colA, valA, big, vsum, n);
    gemmF<128, 96, true, false><<<gB, 256, 0, stream>>>(big, 128, 128, big, 128,
        W1, b1, nullptr, nullptr, h, bsum, bsumsq, n);

    // Layers 2-4
    fold_kernel<96><<<1, 256, 0, stream>>>(W2, bsum, bsumsq, Wf, cb, n);
    aggP<3, false><<<ga, 256, 0, stream>>>(h, 96, offs, colA, valA, big, nullptr, n);
    gemmF<96, 96, true, true><<<gB, 256, 0, stream>>>(big, 96, 96, big, 96,
        Wf, b2, cb, vsum, h, bsum, bsumsq, n);

    fold_kernel<96><<<1, 256, 0, stream>>>(W3, bsum, bsumsq, Wf, cb, n);
    aggP<3, false><<<ga, 256, 0, stream>>>(h, 96, offs, colA, valA, big, nullptr, n);
    gemmF<96, 96, true, true><<<gB, 256, 0, stream>>>(big, 96, 96, big, 96,
        Wf, b3, cb, vsum, h, bsum, bsumsq, n);

    fold_kernel<96><<<1, 256, 0, stream>>>(W4, bsum, bsumsq, Wf, cb, n);
    aggP<3, false><<<ga, 256, 0, stream>>>(h, 96, offs, colA, valA, big, nullptr, n);
    gemmF<96, 96, true, true><<<gB, 256, 0, stream>>>(big, 96, 96, big, 96,
        Wf, b4, cb, vsum, h, bsum, bsumsq, n);

    // Layer 5 (96 -> 64, no BN stats after)
    fold_kernel<64><<<1, 256, 0, stream>>>(W5, bsum, bsumsq, Wf, cb, n);
    aggP<3, false><<<ga, 256, 0, stream>>>(h, 96, offs, colA, valA, big, nullptr, n);
    gemmF<96, 64, false, true><<<gB, 256, 0, stream>>>(big, 96, 96, big, 96,
        Wf, b5, cb, vsum, h, bsum, bsumsq, n);

    // MLP
    gemmF<96, 128, false, false><<<gB, 256, 0, stream>>>(h, 64, 64, x + 128, XLD,
        M1w, M1b, nullptr, nullptr, big, bsum, bsumsq, n);
    gemmF<128, 64, false, false><<<gB, 256, 0, stream>>>(big, 128, 128, big, 128,
        M2w, M2b, nullptr, nullptr, h, bsum, bsumsq, n);

    // m = a2 @ M3w + M3b ; global min
    dot_min_kernel<<<256, 256, 0, stream>>>(h, M3w, M3b, m, gmin, n);

    // where(grp==0, min, m)
    where_kernel<<<(n + 255) / 256, 256, 0, stream>>>(x, m, gmin, n);

    // exact 71st-largest threshold
    select_kernel<<<1, 1024, 0, stream>>>(m, n, 71, thresh);

    // out = m>thresh ? m*(1/m) : 0
    mask_kernel<<<(n + 255) / 256, 256, 0, stream>>>(m, thresh, (float*)d_out, n);
}